// Round 9
// baseline (479.975 us; speedup 1.0000x reference)
//
#include <hip/hip_runtime.h>
#include <hip/hip_bf16.h>

// Problem constants (fixed by the reference)
constexpr int M_ = 8192;      // batch
constexpr int N_ = 4096;      // out_dim
constexpr int K_ = 4096;      // in_dim
constexpr int CBOOK = 65536;
constexpr int HA = 10007, HB = 20011;
constexpr int HC3 = 3 * 40009;     // 120027
// sign hash: all constants odd => sign = +1 iff (o+i) even

// Algebra (CBOOK = 2^16, HB odd => invertible mod 2^16):
//   197*HB ≡ HA (mod 2^16)  =>  idx(n,k) = (U*HB + HC3) & 0xFFFF,
//   U = (197n + k) & 0xFFFF; parity(U) = parity(n+k) => sign folds into U.
//   W[n][k] = P2ext[(197n+k) & 0xFFFF],
//   P2ext[u] = (u&1 ? -1 : +1) * cb[(u*HB + HC3) & 0xFFFF]   (65536-periodic)
// Used ONLY in prep (one aligned 16B load per output slot instead of 8
// scattered cb gathers).
constexpr int C0 = 197;

constexpr int BM = 256, BN = 256, BK = 32;
constexpr int NKT = K_ / BK;               // 128 K-tiles

using bf16x8 = __bf16 __attribute__((ext_vector_type(8)));
using f32x4  = float __attribute__((ext_vector_type(4)));
using u16x8  = unsigned short __attribute__((ext_vector_type(8)));

typedef __attribute__((address_space(3))) void lds_void_t;
typedef const __attribute__((address_space(1))) void gbl_void_t;

static __device__ __forceinline__ unsigned short f2bf(float f) {
    __bf16 h = (__bf16)f;   // RNE on gfx950
    return __builtin_bit_cast(unsigned short, h);
}

// ---------------------------------------------------------------------------
// prep stage 1: P2 phase-copy table  P2p[p][i] = P2ext[i+p], p<8, i<65536.
// 1 MiB; gives every (lane,slot) a 16B-aligned contiguous window of P2ext.
// ---------------------------------------------------------------------------
constexpr int P2N   = 8 * 65536;           // 524288 elems, 1 MiB
constexpr int P2B   = P2N / 256;           // 2048 blocks

__global__ __launch_bounds__(256) void prep_p2(const float* __restrict__ cb,
                                               unsigned short* __restrict__ P2p) {
    const int t = blockIdx.x * 256 + threadIdx.x;   // [0, 2^19)
    const int p = t >> 16;
    const int i = t & 65535;
    const int u = i + p;                            // u*HB < 2^31
    float v = cb[(u * HB + HC3) & (CBOOK - 1)];
    if (u & 1) v = -v;
    P2p[t] = f2bf(v);
}

// ---------------------------------------------------------------------------
// prep stage 2 (merged):
//   blocks [0, GENB): W in MFMA B-fragment-flat order (R0-proven layout):
//     Wf[((ntile*128 + kt)*64 + lane)*8 + j] = W[n][k],
//       n = ntile*16 + (lane&15), k = kt*32 + (lane>>4)*8 + j
//     (matches mfma_f32_16x16x32_bf16 B-operand: lane holds W[n][k..k+8))
//     via one aligned 16B P2p load: u0 = (197n+k0)&0xFFFF.
//   blocks [GENB, GENB+CONVB): x fp32 -> bf16 row-major (A staging source)
// ---------------------------------------------------------------------------
constexpr int GENB  = N_ * K_ / 8 / 256;   // 8192
constexpr int CONVB = M_ * K_ / 8 / 256;   // 16384

__global__ __launch_bounds__(256) void prep_main(const float* __restrict__ x,
                                                 const unsigned short* __restrict__ P2p,
                                                 unsigned short* __restrict__ Wf,
                                                 unsigned short* __restrict__ xb) {
    const int b = blockIdx.x;
    if (b < GENB) {
        const int t     = b * 256 + threadIdx.x;   // [0, 2^21) 16B slots
        const int lane  = t & 63;
        const int kt    = (t >> 6) & 127;
        const int ntile = t >> 13;
        const int n  = (ntile << 4) + (lane & 15);
        const int k0 = (kt << 5) + ((lane >> 4) << 3);
        const int u0 = (C0 * n + k0) & (CBOOK - 1);
        const u16x8 w = *reinterpret_cast<const u16x8*>(
            P2p + ((u0 & 7) << 16) + (u0 & 65528));     // one aligned 16B load
        *reinterpret_cast<u16x8*>(&Wf[(size_t)t * 8]) = w;   // coalesced
    } else {
        const size_t t = (size_t)(b - GENB) * 256 + threadIdx.x;
        const float4* p = reinterpret_cast<const float4*>(x) + t * 2;
        const float4 a = p[0], c = p[1];
        u16x8 out;
        out[0] = f2bf(a.x); out[1] = f2bf(a.y); out[2] = f2bf(a.z); out[3] = f2bf(a.w);
        out[4] = f2bf(c.x); out[5] = f2bf(c.y); out[6] = f2bf(c.z); out[7] = f2bf(c.w);
        reinterpret_cast<u16x8*>(xb)[t] = out;
    }
}

// ---------------------------------------------------------------------------
// GEMM: C[M][N] = A[M][K] * W[N][K]^T + bias
// 256x256 tile, BK=32, 512 threads (8 waves 2Mx4N, wave tile 128x64).
// A: 4-deep LDS ring (64 KB), global_load_lds, conflict-free swizzled reads.
// B: NO LDS — fragment-flat Wf read L2->VGPR (4 x 1KB coalesced loads/wave/
//    window, double-buffered bfrE/bfrO, 1-window prefetch).  This halves the
//    LDS pipe (R7 showed LDS wall ~1280-1530 cyc ~= MFMA wall 1242 -> the
//    two co-equal pipes bounded util at ~57%; now LDS ~830 << 1242).
//    B redundancy only 2x (wm pairs), ~32KB/window/CU from L2-resident slice.
// Sync per window kt (ONE barrier):
//   vmcnt(6) -> s_barrier -> STAGE_A(kt+3) + BLOAD(kt+1) -> MFMA cluster
//   with afr[mt] reloads for kt+1 interleaved at register-death points.
//   vmcnt(6) is order-robust: the newest 6 VMEM ops are always the previous
//   window's {STAGE 2, BLOAD 4}, so it certifies STAGE(kt+1) (tail-read
//   target) regardless of intra-window issue order.  bfr register uses get
//   compiler-inserted counted waits (R0-proven pattern on this toolchain).
// Cross-wave LDS WAR: reads of slot (kt+1)&3 retire before MFMA(kt+1)
// (lgkm), hence before barrier(kt+2), hence before STAGE(kt+5) rewrites it.
// ---------------------------------------------------------------------------
__global__ __launch_bounds__(512, 2) void gemm_kernel(
        const unsigned short* __restrict__ A,    // xb row-major [M][K]
        const unsigned short* __restrict__ Wf,   // fragment-flat W
        const float* __restrict__ bias,
        float* __restrict__ C) {
    __shared__ __align__(16) unsigned short As[4 * 8192];   // 64 KB (A ring)

    const int tid  = threadIdx.x;
    const int lane = tid & 63;
    const int w    = tid >> 6;          // wave 0..7
    const int wm   = w >> 2;            // 0..1 -> rows wm*128
    const int wn   = w & 3;             // 0..3 -> cols wn*64
    const int m0 = blockIdx.y * BM;
    const int n0 = blockIdx.x * BN;

    const int quad = lane >> 4;         // 0..3
    const int l16  = lane & 15;

    // --- A staging addressing (slot s = r*512 + tid: row=s>>2, blk=s&3,
    //     swizzle key=(row>>1)&3 baked into the source column) ---
    const int sblk = (lane & 3) ^ ((lane >> 3) & 3);
    const unsigned short* aLane =
        A + (size_t)(m0 + w * 16 + (lane >> 2)) * K_ + sblk * 8;
    // --- B fragment-flat base: fragment (nt,kt) of this wave's col block ---
    const unsigned short* bWave =
        Wf + (size_t)(blockIdx.x * 16 + wn * 4) * NKT * 512 + lane * 8;

    // --- A ds-read addressing (swizzled, 2-way max -> conflict-free) ---
    const int rblk = (quad ^ ((l16 >> 1) & 3)) * 8;
    const unsigned short* aRd = As + (wm * 128 + l16) * 32 + rblk;

    f32x4 acc[8][4] = {};               // wave tile 128x64 (AGPRs)
    bf16x8 afr[8];                      // A fragments (current window)
    bf16x8 bfrE[4], bfrO[4];            // B fragments, even/odd window

    // stage A K-tile kt into ring slot bs (2 vmem loads per wave)
    auto STAGE = [&](int kt, int bs) {
#pragma unroll
        for (int r = 0; r < 2; ++r)
            __builtin_amdgcn_global_load_lds(
                (gbl_void_t*)(aLane + (size_t)r * 128 * K_ + (size_t)kt * BK),
                (lds_void_t*)(As + bs * 8192 + (r * 512 + w * 64) * 8), 16, 0, 0);
    };
    // load B fragments of K-tile kt straight from L2 into dst
    auto BLOAD = [&](int kt, bf16x8 (&dst)[4]) {
#pragma unroll
        for (int nt = 0; nt < 4; ++nt)
            dst[nt] = *reinterpret_cast<const bf16x8*>(
                bWave + ((size_t)nt * NKT + kt) * 512);
    };

    STAGE(0, 0); STAGE(1, 1); STAGE(2, 2);
    BLOAD(0, bfrE);
    asm volatile("s_waitcnt vmcnt(0)" ::: "memory");   // one-time full cert
    __builtin_amdgcn_s_barrier();
    // preload A fragments of K-tile 0 (slot 0)
#pragma unroll
    for (int mt = 0; mt < 8; ++mt)
        afr[mt] = *reinterpret_cast<const bf16x8*>(aRd + mt * 512);

    for (int kt0 = 0; kt0 < NKT; kt0 += 4) {
#pragma unroll
        for (int s = 0; s < 4; ++s) {
            const int kt = kt0 + s;
            // order-robust cert: newest 6 = previous window's {STAGE,BLOAD};
            // everything older (incl. STAGE(kt+1)) is certified landed.
            asm volatile("s_waitcnt vmcnt(6)" ::: "memory");
            __builtin_amdgcn_s_barrier();            // open window kt

            if (kt + 3 < NKT) STAGE(kt + 3, (s + 3) & 3);
            if (kt + 1 < NKT) {
                if (s & 1) BLOAD(kt + 1, bfrE); else BLOAD(kt + 1, bfrO);
            }

            const int rs = ((s + 1) & 3) * 8192;     // afr reload slot (imm)
            __builtin_amdgcn_s_setprio(1);
#pragma unroll
            for (int mt = 0; mt < 8; ++mt) {
#pragma unroll
                for (int nt = 0; nt < 4; ++nt)
                    acc[mt][nt] = __builtin_amdgcn_mfma_f32_16x16x32_bf16(
                        afr[mt], (s & 1) ? bfrO[nt] : bfrE[nt],
                        acc[mt][nt], 0, 0, 0);
                // afr[mt] dead now: reload for window kt+1 (slot certified at
                // this window's open; at kt=NKT-1 reads stale data, never used)
                afr[mt] = *reinterpret_cast<const bf16x8*>(aRd + rs + mt * 512);
            }
            __builtin_amdgcn_s_setprio(0);
        }
    }

    // epilogue: C/D layout col=lane&15, row=quad*4+r (m89/m91-verified)
#pragma unroll
    for (int nt = 0; nt < 4; ++nt) {
        const int col = n0 + wn * 64 + nt * 16 + l16;
        const float bv = bias[col];
#pragma unroll
        for (int mt = 0; mt < 8; ++mt) {
            const int rowb = m0 + wm * 128 + mt * 16 + quad * 4;
#pragma unroll
            for (int r = 0; r < 4; ++r)
                C[(size_t)(rowb + r) * N_ + col] = acc[mt][nt][r] + bv;
        }
    }
}

// ---------------------------------------------------------------------------
// Correctness-insurance fallback (only if ws too small; slow but exact)
// ---------------------------------------------------------------------------
__global__ __launch_bounds__(256) void naive_kernel(const float* __restrict__ x,
                                                    const float* __restrict__ cb,
                                                    const float* __restrict__ bias,
                                                    float* __restrict__ out) {
    const size_t t = (size_t)blockIdx.x * 256 + threadIdx.x;
    const int row = (int)(t / N_);
    const int col = (int)(t % N_);
    float s = bias[col];
    const float* xr = x + (size_t)row * K_;
    const int h = col * HA + HC3;
    for (int i = 0; i < K_; ++i) {
        float v = cb[(h + i * HB) & (CBOOK - 1)];
        s += xr[i] * (((col ^ i) & 1) ? -v : v);
    }
    out[t] = s;
}

extern "C" void kernel_launch(void* const* d_in, const int* in_sizes, int n_in,
                              void* d_out, int out_size, void* d_ws, size_t ws_size,
                              hipStream_t stream) {
    const float* x    = (const float*)d_in[0];
    const float* cb   = (const float*)d_in[1];
    const float* bias = (const float*)d_in[2];
    float* out = (float*)d_out;

    const size_t wBytes = (size_t)N_ * K_ * sizeof(unsigned short);  // 32 MiB
    const size_t xBytes = (size_t)M_ * K_ * sizeof(unsigned short);  // 64 MiB
    const size_t pBytes = (size_t)P2N * sizeof(unsigned short);      // 1 MiB

    if (ws_size >= wBytes + xBytes + pBytes) {
        unsigned short* Wf  = (unsigned short*)d_ws;
        unsigned short* xb  = (unsigned short*)((char*)d_ws + wBytes);
        unsigned short* P2p = (unsigned short*)((char*)d_ws + wBytes + xBytes);
        prep_p2<<<P2B, 256, 0, stream>>>(cb, P2p);
        prep_main<<<GENB + CONVB, 256, 0, stream>>>(x, P2p, Wf, xb);
        // grid x = 16 n-strips: XCD = linear%8 = x%8; each XCD's Wf slice is
        // 2 strips x 2MB = 4MB = its L2.  B stream stays L2/L3-resident.
        gemm_kernel<<<dim3(N_ / BN, M_ / BM), 512, 0, stream>>>(xb, Wf, bias, out);
    } else {
        naive_kernel<<<(int)((size_t)M_ * N_ / 256), 256, 0, stream>>>(x, cb, bias, out);
    }
}

// Round 10
// 453.380 us; speedup vs baseline: 1.0587x; 1.0587x over previous
//
#include <hip/hip_runtime.h>
#include <hip/hip_bf16.h>

// Problem constants (fixed by the reference)
constexpr int M_ = 8192;      // batch
constexpr int N_ = 4096;      // out_dim
constexpr int K_ = 4096;      // in_dim
constexpr int CBOOK = 65536;
constexpr int HA = 10007, HB = 20011;
constexpr int HC3 = 3 * 40009;     // 120027
// sign hash: all constants odd => sign = +1 iff (o+i) even

// Algebra (CBOOK = 2^16, HB odd => invertible mod 2^16):
//   197*HB ≡ HA (mod 2^16)  =>  idx(n,k) = (U*HB + HC3) & 0xFFFF,
//   U = (197n + k) & 0xFFFF; parity(U) = parity(n+k) => sign folds into U.
//   W[n][k] = P2ext[(197n+k) & 0xFFFF],
//   P2ext[u] = (u&1 ? -1 : +1) * cb[(u*HB + HC3) & 0xFFFF]   (65536-periodic)
// Used ONLY in prep (one aligned 16B load per output slot instead of 8
// scattered cb gathers); the GEMM reads a linear pre-swizzled W image.
constexpr int C0 = 197;

constexpr int BM = 256, BN = 256, BK = 32;
constexpr int NKT = K_ / BK;               // 128 K-tiles

using bf16x8 = __bf16 __attribute__((ext_vector_type(8)));
using f32x4  = float __attribute__((ext_vector_type(4)));
using u16x8  = unsigned short __attribute__((ext_vector_type(8)));

typedef __attribute__((address_space(3))) void lds_void_t;
typedef const __attribute__((address_space(1))) void gbl_void_t;

static __device__ __forceinline__ unsigned short f2bf(float f) {
    __bf16 h = (__bf16)f;   // RNE on gfx950
    return __builtin_bit_cast(unsigned short, h);
}

// ---------------------------------------------------------------------------
// prep stage 1: P2 phase-copy table  P2p[p][i] = P2ext[i+p], p<8, i<65536.
// 1 MiB; gives every (lane,slot) a 16B-aligned contiguous window of P2ext.
// ---------------------------------------------------------------------------
constexpr int P2N   = 8 * 65536;           // 524288 elems, 1 MiB
constexpr int P2B   = P2N / 256;           // 2048 blocks

__global__ __launch_bounds__(256) void prep_p2(const float* __restrict__ cb,
                                               unsigned short* __restrict__ P2p) {
    const int t = blockIdx.x * 256 + threadIdx.x;   // [0, 2^19)
    const int p = t >> 16;
    const int i = t & 65535;
    const int u = i + p;                            // u*HB < 2^31
    float v = cb[(u * HB + HC3) & (CBOOK - 1)];
    if (u & 1) v = -v;
    P2p[t] = f2bf(v);
}

// ---------------------------------------------------------------------------
// prep stage 2 (merged):
//   blocks [0, GENB): W in LDS-image order (swizzle baked in), via P2p:
//     slot t: row = (t&1023)>>2, blk = t&3, kt = (t>>10)&127, nb = t>>17
//     key = (row>>1)&3; n = nb*256+row; k0 = kt*32 + ((blk^key)<<3)
//     u0 = (197n + k0) & 0xFFFF;  out[j] = P2ext[u0+j] = P2p[u0&7][u0&~7 + j]
//   blocks [GENB, GENB+CONVB): x fp32 -> bf16 row-major (A staging source)
// ---------------------------------------------------------------------------
constexpr int GENB  = N_ * K_ / 8 / 256;   // 8192
constexpr int CONVB = M_ * K_ / 8 / 256;   // 16384

__global__ __launch_bounds__(256) void prep_main(const float* __restrict__ x,
                                                 const unsigned short* __restrict__ P2p,
                                                 unsigned short* __restrict__ Wf,
                                                 unsigned short* __restrict__ xb) {
    const int b = blockIdx.x;
    if (b < GENB) {
        const int t    = b * 256 + threadIdx.x;   // [0, 2^21) 16B slots
        const int slot = t & 1023;
        const int kt   = (t >> 10) & 127;
        const int nb   = t >> 17;
        const int row  = slot >> 2;
        const int key  = (row >> 1) & 3;
        const int n  = (nb << 8) + row;
        const int k0 = (kt << 5) + (((slot & 3) ^ key) << 3);
        const int u0 = (C0 * n + k0) & (CBOOK - 1);
        const u16x8 w = *reinterpret_cast<const u16x8*>(
            P2p + ((u0 & 7) << 16) + (u0 & 65528));     // one aligned 16B load
        *reinterpret_cast<u16x8*>(&Wf[(size_t)t * 8]) = w;   // coalesced
    } else {
        const size_t t = (size_t)(b - GENB) * 256 + threadIdx.x;
        const float4* p = reinterpret_cast<const float4*>(x) + t * 2;
        const float4 a = p[0], c = p[1];
        u16x8 out;
        out[0] = f2bf(a.x); out[1] = f2bf(a.y); out[2] = f2bf(a.z); out[3] = f2bf(a.w);
        out[4] = f2bf(c.x); out[5] = f2bf(c.y); out[6] = f2bf(c.z); out[7] = f2bf(c.w);
        reinterpret_cast<u16x8*>(xb)[t] = out;
    }
}

// ---------------------------------------------------------------------------
// GEMM: C[M][N] = A[M][K] * W[N][K]^T + bias
// 256x256 tile, BK=32, 512 threads (8 waves 2Mx4N, wave tile 128x64).
// 4-deep LDS ring (128 KB), both operands LDS-staged (R6-proven dataflow).
// R9 deltas vs R6 (both removing exposed non-MFMA cycles, dataflow intact):
//  (1) bfr register DOUBLE-BUFFER (bfrE/bfrO, +16 VGPR, occupancy-neutral):
//      all 12 ds_reads for tile kt+1 now interleave inside cluster(kt) at
//      register-death points -> no 4-read tail, no lgkm stall at the next
//      cluster's first MFMA (>=620 cyc slack on every operand read).
//  (2) 2-window SYNC BATCHES: one {vmcnt(0); s_barrier; 2x STAGE} per tile
//      pair (s=0 and s=2 of the x4-unrolled loop) -> 64 barriers+waits
//      instead of 128.  Cert ledger: batch {kt0} stages {kt0+3->slot3,
//      kt0+4->slot0}; batch {kt0+2} stages {kt0+5->slot1, kt0+6->slot2}.
//      Every cluster(t)'s reloads read slot (t+1)&3, staged >= 2 windows
//      earlier and certified by the latest vmcnt(0) (issue-to-cert slack
//      ~4200 cyc >> 900 cyc HBM, so the drain retires immediately).
//      Every slot overwrite is separated from its last reader by a barrier
//      (reader: reg-preload of that tile during an earlier window).
// ---------------------------------------------------------------------------
__global__ __launch_bounds__(512, 2) void gemm_kernel(
        const unsigned short* __restrict__ A,    // xb row-major [M][K]
        const unsigned short* __restrict__ Wf,   // LDS-image W
        const float* __restrict__ bias,
        float* __restrict__ C) {
    __shared__ __align__(16) unsigned short sm[4 * 8192 * 2];  // 128 KB
    unsigned short* As = sm;                 // [4][8192]
    unsigned short* Bs = sm + 4 * 8192;      // [4][8192]

    const int tid  = threadIdx.x;
    const int lane = tid & 63;
    const int w    = tid >> 6;          // wave 0..7
    const int wm   = w >> 2;            // 0..1 -> rows wm*128
    const int wn   = w & 3;             // 0..3 -> cols wn*64
    const int m0 = blockIdx.y * BM;
    const int n0 = blockIdx.x * BN;

    const int quad = lane >> 4;         // 0..3
    const int l16  = lane & 15;

    // --- staging addressing (slot s = r*512 + tid: row=s>>2, blk=s&3,
    //     swizzle key=(row>>1)&3 baked into both source layouts) ---
    const int sblk = (lane & 3) ^ ((lane >> 3) & 3);
    const unsigned short* aLane =
        A + (size_t)(m0 + w * 16 + (lane >> 2)) * K_ + sblk * 8;
    const unsigned short* bLane =
        Wf + (size_t)blockIdx.x * NKT * 8192 + tid * 8;   // fully linear

    // --- ds-read addressing (swizzled, 2-way max -> conflict-free) ---
    const int rblk = (quad ^ ((l16 >> 1) & 3)) * 8;
    const unsigned short* aRd = As + (wm * 128 + l16) * 32 + rblk;
    const unsigned short* bRd = Bs + (wn * 64 + l16) * 32 + rblk;

    f32x4 acc[8][4] = {};               // wave tile 128x64 (AGPRs)
    bf16x8 afr[8];                      // A fragments, reload-at-death
    bf16x8 bfrE[4], bfrO[4];            // B fragments, even/odd window

    // stage K-tile kt into ring slot bs (4 vmem loads per wave)
    auto STAGE = [&](int kt, int bs) {
#pragma unroll
        for (int r = 0; r < 2; ++r) {
            __builtin_amdgcn_global_load_lds(
                (gbl_void_t*)(aLane + (size_t)r * 128 * K_ + (size_t)kt * BK),
                (lds_void_t*)(As + bs * 8192 + (r * 512 + w * 64) * 8), 16, 0, 0);
            __builtin_amdgcn_global_load_lds(
                (gbl_void_t*)(bLane + (size_t)kt * 8192 + r * 4096),
                (lds_void_t*)(Bs + bs * 8192 + (r * 512 + w * 64) * 8), 16, 0, 0);
        }
    };

    STAGE(0, 0); STAGE(1, 1); STAGE(2, 2);
    asm volatile("s_waitcnt vmcnt(0)" ::: "memory");   // prologue full cert
    __builtin_amdgcn_s_barrier();
    // preload tile 0 fragments (slot 0); window 0 is even -> bfrE
#pragma unroll
    for (int nt = 0; nt < 4; ++nt)
        bfrE[nt] = *reinterpret_cast<const bf16x8*>(bRd + nt * 512);
#pragma unroll
    for (int mt = 0; mt < 8; ++mt)
        afr[mt] = *reinterpret_cast<const bf16x8*>(aRd + mt * 512);

    for (int kt0 = 0; kt0 < NKT; kt0 += 4) {
#pragma unroll
        for (int s = 0; s < 4; ++s) {
            if ((s & 1) == 0) {
                // batch open: certify the 2 tiles this batch will preload
                // (staged >= 2 windows ago -> wait retires immediately)
                asm volatile("s_waitcnt vmcnt(0)" ::: "memory");
                __builtin_amdgcn_s_barrier();
                if (s == 0) {
                    if (kt0 + 3 < NKT) STAGE(kt0 + 3, 3);
                    if (kt0 + 4 < NKT) STAGE(kt0 + 4, 0);
                } else {
                    if (kt0 + 5 < NKT) STAGE(kt0 + 5, 1);
                    if (kt0 + 6 < NKT) STAGE(kt0 + 6, 2);
                }
            }

            const int rs = ((s + 1) & 3) * 8192;     // reload slot (imm offs)
            __builtin_amdgcn_s_setprio(1);
#pragma unroll
            for (int mt = 0; mt < 8; ++mt) {
#pragma unroll
                for (int nt = 0; nt < 4; ++nt)
                    acc[mt][nt] = __builtin_amdgcn_mfma_f32_16x16x32_bf16(
                        afr[mt], (s & 1) ? bfrO[nt] : bfrE[nt],
                        acc[mt][nt], 0, 0, 0);
                // afr[mt] dead: reload for window kt+1 (slot certified at the
                // batch open; final window reads stale data, never used)
                afr[mt] = *reinterpret_cast<const bf16x8*>(aRd + rs + mt * 512);
                // next window's B buffer: no WAR with current MFMAs
                if ((mt & 1) == 0) {
                    if (s & 1)
                        bfrE[mt >> 1] = *reinterpret_cast<const bf16x8*>(
                            bRd + rs + (mt >> 1) * 512);
                    else
                        bfrO[mt >> 1] = *reinterpret_cast<const bf16x8*>(
                            bRd + rs + (mt >> 1) * 512);
                }
            }
            __builtin_amdgcn_s_setprio(0);
        }
    }

    // epilogue: C/D layout col=lane&15, row=quad*4+r (m89/m91-verified)
#pragma unroll
    for (int nt = 0; nt < 4; ++nt) {
        const int col = n0 + wn * 64 + nt * 16 + l16;
        const float bv = bias[col];
#pragma unroll
        for (int mt = 0; mt < 8; ++mt) {
            const int rowb = m0 + wm * 128 + mt * 16 + quad * 4;
#pragma unroll
            for (int r = 0; r < 4; ++r)
                C[(size_t)(rowb + r) * N_ + col] = acc[mt][nt][r] + bv;
        }
    }
}

// ---------------------------------------------------------------------------
// Correctness-insurance fallback (only if ws too small; slow but exact)
// ---------------------------------------------------------------------------
__global__ __launch_bounds__(256) void naive_kernel(const float* __restrict__ x,
                                                    const float* __restrict__ cb,
                                                    const float* __restrict__ bias,
                                                    float* __restrict__ out) {
    const size_t t = (size_t)blockIdx.x * 256 + threadIdx.x;
    const int row = (int)(t / N_);
    const int col = (int)(t % N_);
    float s = bias[col];
    const float* xr = x + (size_t)row * K_;
    const int h = col * HA + HC3;
    for (int i = 0; i < K_; ++i) {
        float v = cb[(h + i * HB) & (CBOOK - 1)];
        s += xr[i] * (((col ^ i) & 1) ? -v : v);
    }
    out[t] = s;
}

extern "C" void kernel_launch(void* const* d_in, const int* in_sizes, int n_in,
                              void* d_out, int out_size, void* d_ws, size_t ws_size,
                              hipStream_t stream) {
    const float* x    = (const float*)d_in[0];
    const float* cb   = (const float*)d_in[1];
    const float* bias = (const float*)d_in[2];
    float* out = (float*)d_out;

    const size_t wBytes = (size_t)N_ * K_ * sizeof(unsigned short);  // 32 MiB
    const size_t xBytes = (size_t)M_ * K_ * sizeof(unsigned short);  // 64 MiB
    const size_t pBytes = (size_t)P2N * sizeof(unsigned short);      // 1 MiB

    if (ws_size >= wBytes + xBytes + pBytes) {
        unsigned short* Wf  = (unsigned short*)d_ws;
        unsigned short* xb  = (unsigned short*)((char*)d_ws + wBytes);
        unsigned short* P2p = (unsigned short*)((char*)d_ws + wBytes + xBytes);
        prep_p2<<<P2B, 256, 0, stream>>>(cb, P2p);
        prep_main<<<GENB + CONVB, 256, 0, stream>>>(x, P2p, Wf, xb);
        // grid x = 16 n-strips: XCD = linear%8 = x%8; each XCD's Wf slice is
        // 2 strips x 2MB = 4MB = its L2.  B stream stays L2-resident.
        gemm_kernel<<<dim3(N_ / BN, M_ / BM), 512, 0, stream>>>(xb, Wf, bias, out);
    } else {
        naive_kernel<<<(int)((size_t)M_ * N_ / 256), 256, 0, stream>>>(x, cb, bias, out);
    }
}